// Round 2
// baseline (53363.776 us; speedup 1.0000x reference)
//
#include <hip/hip_runtime.h>
#include <math.h>

#define BB 4096      // total batch
#define SEQ 64       // tokens per board
#define DM 256       // d_model
#define NH 8
#define HDIM 32
#define NL 6
#define FFD 1024
#define NT (BB*SEQ)

// ---------------- positional encoding (64 x 256) ----------------
__global__ void pe_kernel(float* __restrict__ pe) {
  int g = blockIdx.x * 256 + threadIdx.x;
  if (g >= SEQ * DM) return;
  int s = g >> 8, d = g & 255;
  int i = s >> 3, j = s & 7;
  float ex = (float)(d & ~1) * (1.0f / DM);
  float dv = powf(10000.0f, ex);
  pe[g] = (d & 1) ? cosf((float)j / dv) : sinf((float)i / dv);
}

// ---------------- tokenizer: argmax over 14 piece channels (full batch) -----
__global__ void tok_kernel(const float* __restrict__ board, int* __restrict__ toks) {
  int n = blockIdx.x * 256 + threadIdx.x;
  if (n >= NT) return;
  int b = n >> 6, s = n & 63;
  const float* p = board + (size_t)b * (14 * 64) + s;
  float mx = p[0]; int idx = 0;
#pragma unroll
  for (int c = 1; c < 14; ++c) {
    float v = p[(size_t)c * 64];
    if (v > mx) { mx = v; idx = c; }   // strict > keeps first occurrence (jnp.argmax)
  }
  toks[n] = (mx > 0.0f) ? idx + 1 : 0;
}

// ---------------- x = emb[tok] + pe  (chunk) ----------------
__global__ void embed_kernel(const int* __restrict__ toks, const float* __restrict__ emb,
                             const float* __restrict__ pe, float* __restrict__ x, int cnt) {
  int g = blockIdx.x * 256 + threadIdx.x;   // one float4 per thread
  if (g >= cnt * (DM / 4)) return;
  int n = g >> 6, q = g & 63;
  int s = n & 63;
  int tok = toks[n];
  float4 e = *(const float4*)(emb + (size_t)tok * DM + q * 4);
  float4 p = *(const float4*)(pe + (size_t)s * DM + q * 4);
  float4 r; r.x = e.x + p.x; r.y = e.y + p.y; r.z = e.z + p.z; r.w = e.w + p.w;
  *(float4*)(x + (size_t)n * DM + q * 4) = r;
}

// ---------------- generic fp32 GEMM: C[M,N] = A[M,K] @ W[N,K]^T (+bias)(+relu) ----
// 64x64 block tile, BK=32, 256 threads, 4x4 microtile. M,N multiples of 64; K of 32.
template<bool BIAS, bool RELU>
__global__ __launch_bounds__(256) void gemm_f32(
    const float* __restrict__ A, const float* __restrict__ W,
    const float* __restrict__ bias, float* __restrict__ C,
    int M, int N, int K)
{
  __shared__ float As[32][68];   // [k][m], pad 68: 16B-aligned rows, spreads banks
  __shared__ float Bs[32][68];   // [k][n]
  const int bm = blockIdx.x * 64;
  const int bn = blockIdx.y * 64;
  const int tid = threadIdx.x;
  const int lr = tid >> 3;          // 0..31
  const int lc = (tid & 7) * 4;     // 0..28 (k offset, float4)
  const int ty = tid >> 4;          // 0..15 (m)
  const int tx = tid & 15;          // 0..15 (n)
  float acc[4][4] = {{0.f}};

  for (int k0 = 0; k0 < K; k0 += 32) {
#pragma unroll
    for (int p = 0; p < 2; ++p) {
      int r = lr + p * 32;
      float4 av = *(const float4*)(A + (size_t)(bm + r) * K + k0 + lc);
      As[lc + 0][r] = av.x; As[lc + 1][r] = av.y; As[lc + 2][r] = av.z; As[lc + 3][r] = av.w;
      float4 wv = *(const float4*)(W + (size_t)(bn + r) * K + k0 + lc);
      Bs[lc + 0][r] = wv.x; Bs[lc + 1][r] = wv.y; Bs[lc + 2][r] = wv.z; Bs[lc + 3][r] = wv.w;
    }
    __syncthreads();
#pragma unroll
    for (int k = 0; k < 32; ++k) {
      float4 a = *(const float4*)&As[k][ty * 4];
      float4 b = *(const float4*)&Bs[k][tx * 4];
      acc[0][0] += a.x * b.x; acc[0][1] += a.x * b.y; acc[0][2] += a.x * b.z; acc[0][3] += a.x * b.w;
      acc[1][0] += a.y * b.x; acc[1][1] += a.y * b.y; acc[1][2] += a.y * b.z; acc[1][3] += a.y * b.w;
      acc[2][0] += a.z * b.x; acc[2][1] += a.z * b.y; acc[2][2] += a.z * b.z; acc[2][3] += a.z * b.w;
      acc[3][0] += a.w * b.x; acc[3][1] += a.w * b.y; acc[3][2] += a.w * b.z; acc[3][3] += a.w * b.w;
    }
    __syncthreads();
  }

  float4 bv = make_float4(0.f, 0.f, 0.f, 0.f);
  if (BIAS) bv = *(const float4*)(bias + bn + tx * 4);
#pragma unroll
  for (int i = 0; i < 4; ++i) {
    float4 r;
    r.x = acc[i][0] + bv.x; r.y = acc[i][1] + bv.y;
    r.z = acc[i][2] + bv.z; r.w = acc[i][3] + bv.w;
    if (RELU) {
      r.x = fmaxf(r.x, 0.f); r.y = fmaxf(r.y, 0.f);
      r.z = fmaxf(r.z, 0.f); r.w = fmaxf(r.w, 0.f);
    }
    *(float4*)(C + (size_t)(bm + ty * 4 + i) * N + bn + tx * 4) = r;
  }
}

// ---------------- attention: one wave per (board, head) ----------------
// qkv row layout (768): [q(0..255) | k(256..511) | v(512..767)], head h at h*32.
__global__ __launch_bounds__(64) void attn_kernel(const float* __restrict__ qkv,
                                                  float* __restrict__ o) {
  __shared__ float Ks[64][32];
  __shared__ float Vs[64][32];
  int bh = blockIdx.x;
  int b = bh >> 3, h = bh & 7;
  int t = threadIdx.x;
  const size_t base = (size_t)b * 64 * 768 + (size_t)h * 32;

  int lrow = t >> 3;           // 0..7
  int lcol = (t & 7) * 4;      // 0..28
#pragma unroll
  for (int rr = 0; rr < 8; ++rr) {
    int r = rr * 8 + lrow;
    *(float4*)&Ks[r][lcol] = *(const float4*)(qkv + base + (size_t)r * 768 + 256 + lcol);
    *(float4*)&Vs[r][lcol] = *(const float4*)(qkv + base + (size_t)r * 768 + 512 + lcol);
  }
  float q[32];
#pragma unroll
  for (int c = 0; c < 8; ++c)
    *(float4*)&q[c * 4] = *(const float4*)(qkv + base + (size_t)t * 768 + c * 4);
  __syncthreads();

  const float scale = 0.17677669529663687f;  // 1/sqrt(32)
  float sc[64];
#pragma unroll
  for (int jr = 0; jr < 64; ++jr) {
    float s = 0.f;
#pragma unroll
    for (int d = 0; d < 32; ++d) s += q[d] * Ks[jr][d];
    sc[jr] = s * scale;
  }
  float m = sc[0];
#pragma unroll
  for (int jr = 1; jr < 64; ++jr) m = fmaxf(m, sc[jr]);
  float sum = 0.f;
#pragma unroll
  for (int jr = 0; jr < 64; ++jr) { sc[jr] = expf(sc[jr] - m); sum += sc[jr]; }
  float inv = 1.f / sum;

  float oa[32];
#pragma unroll
  for (int d = 0; d < 32; ++d) oa[d] = 0.f;
#pragma unroll
  for (int jr = 0; jr < 64; ++jr) {
    float p = sc[jr];
#pragma unroll
    for (int d = 0; d < 32; ++d) oa[d] += p * Vs[jr][d];
  }
  float* op = o + (size_t)(b * 64 + t) * DM + h * 32;
#pragma unroll
  for (int c = 0; c < 8; ++c) {
    float4 r; r.x = oa[c*4] * inv; r.y = oa[c*4+1] * inv; r.z = oa[c*4+2] * inv; r.w = oa[c*4+3] * inv;
    *(float4*)(op + c * 4) = r;
  }
}

// ---------------- fused residual add + LayerNorm (one wave per row) ----------
__global__ __launch_bounds__(256) void ln_kernel(const float* __restrict__ xin,
                                                 const float* __restrict__ delta,
                                                 const float* __restrict__ g,
                                                 const float* __restrict__ beta,
                                                 float* __restrict__ xout, int nrows) {
  int row = (blockIdx.x * 256 + threadIdx.x) >> 6;
  int lane = threadIdx.x & 63;
  if (row >= nrows) return;
  float4 xv = *(const float4*)(xin + (size_t)row * DM + lane * 4);
  float4 dv = *(const float4*)(delta + (size_t)row * DM + lane * 4);
  float v0 = xv.x + dv.x, v1 = xv.y + dv.y, v2 = xv.z + dv.z, v3 = xv.w + dv.w;
  float s1 = v0 + v1 + v2 + v3;
  float s2 = v0 * v0 + v1 * v1 + v2 * v2 + v3 * v3;
#pragma unroll
  for (int off = 32; off; off >>= 1) {
    s1 += __shfl_xor(s1, off);
    s2 += __shfl_xor(s2, off);
  }
  float mean = s1 * (1.f / DM);
  float var = s2 * (1.f / DM) - mean * mean;
  float r = rsqrtf(var + 1e-5f);
  float4 gv = *(const float4*)(g + lane * 4);
  float4 bv = *(const float4*)(beta + lane * 4);
  float4 outv;
  outv.x = (v0 - mean) * r * gv.x + bv.x;
  outv.y = (v1 - mean) * r * gv.y + bv.y;
  outv.z = (v2 - mean) * r * gv.z + bv.z;
  outv.w = (v3 - mean) * r * gv.w + bv.w;
  *(float4*)(xout + (size_t)row * DM + lane * 4) = outv;
}

// ---------------- mean-pool over the 64 tokens ----------------
__global__ void pool_kernel(const float* __restrict__ x, float* __restrict__ pooled, int nb) {
  int g = blockIdx.x * 256 + threadIdx.x;     // (b, d)
  if (g >= nb * DM) return;
  int b = g >> 8, d = g & 255;
  const float* p = x + (size_t)b * SEQ * DM + d;
  float s = 0.f;
#pragma unroll
  for (int t = 0; t < SEQ; ++t) s += p[(size_t)t * DM];
  pooled[g] = s * (1.f / SEQ);
}

// ---------------- value head final: tanh(h @ vw2^T + b) ----------------
__global__ void value_kernel(const float* __restrict__ h, const float* __restrict__ w,
                             const float* __restrict__ bias, float* __restrict__ out, int nb) {
  int row = (blockIdx.x * 256 + threadIdx.x) >> 6;
  int lane = threadIdx.x & 63;
  if (row >= nb) return;
  float4 hv = *(const float4*)(h + (size_t)row * DM + lane * 4);
  float4 wv = *(const float4*)(w + lane * 4);
  float s = hv.x * wv.x + hv.y * wv.y + hv.z * wv.z + hv.w * wv.w;
#pragma unroll
  for (int off = 32; off; off >>= 1) s += __shfl_xor(s, off);
  if (lane == 0) out[row] = tanhf(s + bias[0]);
}

// ---------------- classification final: h @ cw2^T + b (3 outputs) ----------
__global__ void cls_kernel(const float* __restrict__ h, const float* __restrict__ w,
                           const float* __restrict__ bias, float* __restrict__ out, int nb) {
  int row = (blockIdx.x * 256 + threadIdx.x) >> 6;
  int lane = threadIdx.x & 63;
  if (row >= nb) return;
  float4 hv = *(const float4*)(h + (size_t)row * DM + lane * 4);
#pragma unroll
  for (int j = 0; j < 3; ++j) {
    float4 wv = *(const float4*)(w + (size_t)j * DM + lane * 4);
    float s = hv.x * wv.x + hv.y * wv.y + hv.z * wv.z + hv.w * wv.w;
#pragma unroll
    for (int off = 32; off; off >>= 1) s += __shfl_xor(s, off);
    if (lane == 0) out[(size_t)row * 3 + j] = s + bias[j];
  }
}

extern "C" void kernel_launch(void* const* d_in, const int* in_sizes, int n_in,
                              void* d_out, int out_size, void* d_ws, size_t ws_size,
                              hipStream_t stream) {
  const float* board = (const float*)d_in[0];
  const float* emb   = (const float*)d_in[1];
  const float* qkv_w = (const float*)d_in[2];
  const float* qkv_b = (const float*)d_in[3];
  const float* out_w = (const float*)d_in[4];
  const float* out_b = (const float*)d_in[5];
  const float* ln1_g = (const float*)d_in[6];
  const float* ln1_b = (const float*)d_in[7];
  const float* ln2_g = (const float*)d_in[8];
  const float* ln2_b = (const float*)d_in[9];
  const float* ff1_w = (const float*)d_in[10];
  const float* ff1_b = (const float*)d_in[11];
  const float* ff2_w = (const float*)d_in[12];
  const float* ff2_b = (const float*)d_in[13];
  const float* vw1 = (const float*)d_in[14];
  const float* vb1 = (const float*)d_in[15];
  const float* vw2 = (const float*)d_in[16];
  const float* vb2 = (const float*)d_in[17];
  const float* pw1 = (const float*)d_in[18];
  const float* pb1 = (const float*)d_in[19];
  const float* pw2 = (const float*)d_in[20];
  const float* pb2 = (const float*)d_in[21];
  const float* cw1 = (const float*)d_in[22];
  const float* cb1 = (const float*)d_in[23];
  const float* cw2 = (const float*)d_in[24];
  const float* cb2 = (const float*)d_in[25];
  (void)in_sizes; (void)n_in; (void)out_size;

  // ---- workspace layout: small header + one reusable per-chunk region ----
  // header: pe (64 KB) + toks (1 MB)
  char* ws = (char*)d_ws;
  float* pe       = (float*)(ws + 0);
  int*   toks_all = (int*)  (ws + 65536);
  const size_t header = 1114112;   // 64 KB + 1 MB, 256B-aligned

  // adaptive chunk size: largest CB (boards/chunk) whose scratch fits ws_size.
  // per-chunk bytes = CNT*6144 (x_c 1 KB/row + big_c 4 KB/row + obuf_c 1 KB/row)
  int CB = 2048;   // deliberately capped (< full-batch 1.6 GB layout)
  while (CB > 64 && header + (size_t)CB * 64 * 6144 > ws_size) CB >>= 1;
  const int NCH = BB / CB;
  const int CNT = CB * SEQ;   // token rows per chunk

  float* x_c   = (float*)(ws + header);
  float* big_c = x_c + (size_t)CNT * DM;            // CNT*1024 floats
  float* obuf  = big_c + (size_t)CNT * FFD;         // CNT*256 floats
  // head buffers overlay big_c (free at head time)
  float* pooled = big_c;                            // [CB,256]
  float* ph     = big_c + (size_t)CB * DM;          // [CB,1024]
  float* vh     = ph + (size_t)CB * FFD;            // [CB,256]
  float* chb    = vh + (size_t)CB * DM;             // [CB,256]

  float* out = (float*)d_out;
  float* value_out  = out;                              // [B]
  float* policy_out = out + BB;                         // [B,4096]
  float* cls_out    = out + BB + (size_t)BB * 4096;     // [B,3]

  pe_kernel<<<64, 256, 0, stream>>>(pe);
  tok_kernel<<<NT / 256, 256, 0, stream>>>(board, toks_all);

  for (int c = 0; c < NCH; ++c) {
    const int b0 = c * CB;
    const int* toks_c = toks_all + (size_t)b0 * SEQ;

    embed_kernel<<<CNT / 4, 256, 0, stream>>>(toks_c, emb, pe, x_c, CNT);

    for (int l = 0; l < NL; ++l) {
      gemm_f32<true, false><<<dim3(CNT / 64, 768 / 64), 256, 0, stream>>>(
          x_c, qkv_w + (size_t)l * 768 * DM, qkv_b + (size_t)l * 768, big_c, CNT, 768, DM);
      attn_kernel<<<CB * NH, 64, 0, stream>>>(big_c, obuf);
      gemm_f32<true, false><<<dim3(CNT / 64, DM / 64), 256, 0, stream>>>(
          obuf, out_w + (size_t)l * DM * DM, out_b + (size_t)l * DM, big_c, CNT, DM, DM);
      ln_kernel<<<CNT / 4, 256, 0, stream>>>(x_c, big_c, ln1_g + (size_t)l * DM,
                                             ln1_b + (size_t)l * DM, x_c, CNT);
      gemm_f32<true, true><<<dim3(CNT / 64, FFD / 64), 256, 0, stream>>>(
          x_c, ff1_w + (size_t)l * FFD * DM, ff1_b + (size_t)l * FFD, big_c, CNT, FFD, DM);
      gemm_f32<true, false><<<dim3(CNT / 64, DM / 64), 256, 0, stream>>>(
          big_c, ff2_w + (size_t)l * DM * FFD, ff2_b + (size_t)l * DM, obuf, CNT, DM, FFD);
      ln_kernel<<<CNT / 4, 256, 0, stream>>>(x_c, obuf, ln2_g + (size_t)l * DM,
                                             ln2_b + (size_t)l * DM, x_c, CNT);
    }

    // ---- heads for this chunk ----
    pool_kernel<<<CB, 256, 0, stream>>>(x_c, pooled, CB);

    gemm_f32<true, true><<<dim3(CB / 64, DM / 64), 256, 0, stream>>>(
        pooled, vw1, vb1, vh, CB, DM, DM);
    value_kernel<<<CB / 4, 256, 0, stream>>>(vh, vw2, vb2, value_out + b0, CB);

    // policy: x_c flat [CB, 16384] @ pw1^T -> ph [CB,1024]; ph @ pw2^T -> out
    gemm_f32<true, true><<<dim3(CB / 64, FFD / 64), 256, 0, stream>>>(
        x_c, pw1, pb1, ph, CB, FFD, DM * SEQ);
    gemm_f32<true, false><<<dim3(CB / 64, 4096 / 64), 256, 0, stream>>>(
        ph, pw2, pb2, policy_out + (size_t)b0 * 4096, CB, 4096, FFD);

    gemm_f32<true, true><<<dim3(CB / 64, DM / 64), 256, 0, stream>>>(
        pooled, cw1, cb1, chb, CB, DM, DM);
    cls_kernel<<<CB / 4, 256, 0, stream>>>(chb, cw2, cb2, cls_out + (size_t)b0 * 3, CB);
  }
}

// Round 3
// 16985.269 us; speedup vs baseline: 3.1418x; 3.1418x over previous
//
#include <hip/hip_runtime.h>
#include <math.h>

#define BB 4096      // total batch
#define SEQ 64       // tokens per board
#define DM 256       // d_model
#define NH 8
#define HDIM 32
#define NL 6
#define FFD 1024
#define NT (BB*SEQ)

typedef __attribute__((ext_vector_type(8))) short bf16x8;
typedef __attribute__((ext_vector_type(4))) float f32x4;
typedef __attribute__((ext_vector_type(8))) unsigned short u16x8;

__device__ __forceinline__ unsigned short f2bf(float f) {
  unsigned u = __float_as_uint(f);
  unsigned r = u + 0x7FFFu + ((u >> 16) & 1u);   // RNE
  return (unsigned short)(r >> 16);
}
__device__ __forceinline__ float bf2f(unsigned short h) {
  return __uint_as_float(((unsigned)h) << 16);
}
__device__ __forceinline__ void gload_lds16(const void* g, void* l) {
  __builtin_amdgcn_global_load_lds((const __attribute__((address_space(1))) unsigned*)g,
                                   (__attribute__((address_space(3))) unsigned*)l, 16, 0, 0);
}

// ---------------- positional encoding (64 x 256) ----------------
__global__ void pe_kernel(float* __restrict__ pe) {
  int g = blockIdx.x * 256 + threadIdx.x;
  if (g >= SEQ * DM) return;
  int s = g >> 8, d = g & 255;
  int i = s >> 3, j = s & 7;
  float ex = (float)(d & ~1) * (1.0f / DM);
  float dv = powf(10000.0f, ex);
  pe[g] = (d & 1) ? cosf((float)j / dv) : sinf((float)i / dv);
}

// ---------------- tokenizer ----------------
__global__ void tok_kernel(const float* __restrict__ board, int* __restrict__ toks) {
  int n = blockIdx.x * 256 + threadIdx.x;
  if (n >= NT) return;
  int b = n >> 6, s = n & 63;
  const float* p = board + (size_t)b * (14 * 64) + s;
  float mx = p[0]; int idx = 0;
#pragma unroll
  for (int c = 1; c < 14; ++c) {
    float v = p[(size_t)c * 64];
    if (v > mx) { mx = v; idx = c; }
  }
  toks[n] = (mx > 0.0f) ? idx + 1 : 0;
}

// ---------------- weight f32 -> bf16 ----------------
__global__ void cvt_kernel(const float* __restrict__ src, unsigned short* __restrict__ dst, int n4) {
  int g = blockIdx.x * 256 + threadIdx.x;
  if (g >= n4) return;
  float4 v = *(const float4*)(src + (size_t)g * 4);
  ushort4 r;
  r.x = f2bf(v.x); r.y = f2bf(v.y); r.z = f2bf(v.z); r.w = f2bf(v.w);
  *(ushort4*)(dst + (size_t)g * 4) = r;
}

// ---------------- x = emb[tok] + pe  (writes f32 + bf16) ----------------
__global__ void embed_kernel(const int* __restrict__ toks, const float* __restrict__ emb,
                             const float* __restrict__ pe, float* __restrict__ x,
                             unsigned short* __restrict__ xbf, int cnt) {
  int g = blockIdx.x * 256 + threadIdx.x;
  if (g >= cnt * (DM / 4)) return;
  int n = g >> 6, q = g & 63;
  int s = n & 63;
  int tok = toks[n];
  float4 e = *(const float4*)(emb + (size_t)tok * DM + q * 4);
  float4 p = *(const float4*)(pe + (size_t)s * DM + q * 4);
  float4 r; r.x = e.x + p.x; r.y = e.y + p.y; r.z = e.z + p.z; r.w = e.w + p.w;
  *(float4*)(x + (size_t)n * DM + q * 4) = r;
  ushort4 h; h.x = f2bf(r.x); h.y = f2bf(r.y); h.z = f2bf(r.z); h.w = f2bf(r.w);
  *(ushort4*)(xbf + (size_t)n * DM + q * 4) = h;
}

// ============ bf16 MFMA GEMM: C[M,N] = A[M,K]@W[N,K]^T (+bias)(+relu) ============
// BM=BN=128, BK=64, 256 threads (4 waves, 2x2 wave grid, 64x64 per wave).
// A,W bf16 row-major. LDS tiles staged via global_load_lds with XOR-swizzled
// source (involution: byte ^= (row&7)<<4 within each row's 128B), linear dest;
// ds_read_b128 applies the same swizzle -> ~2-way max bank aliasing (free).
template<bool OUTBF, bool RELU, bool BIAS>
__global__ __launch_bounds__(256) void gemm_bf16(
    const unsigned short* __restrict__ A, const unsigned short* __restrict__ W,
    const float* __restrict__ bias, void* __restrict__ Cout,
    int M, int N, int K)
{
  __shared__ __align__(16) short As[128 * 64];   // 16 KB
  __shared__ __align__(16) short Bs[128 * 64];   // 16 KB
  const int bm = blockIdx.x * 128;
  const int bn = blockIdx.y * 128;
  const int tid = threadIdx.x;
  const int lane = tid & 63;
  const int wave = tid >> 6;
  const int wr = wave >> 1, wc = wave & 1;
  const int lo16 = lane & 15, hi4 = lane >> 4;

  // staging coords (per thread): 16B chunk i covers tile row tr, swizzled col16
  const int tr = tid >> 3;               // 0..31, +32 per iter
  const int sc_lin = tid & 7;            // linear col16
  // fragment read coords
  const int arow = wr * 64 + lo16;
  const int brow = wc * 64 + lo16;
  const int amask = (arow & 7) << 4;
  const int bmask = (brow & 7) << 4;

  f32x4 acc[4][4];
#pragma unroll
  for (int m = 0; m < 4; ++m)
#pragma unroll
    for (int n = 0; n < 4; ++n) acc[m][n] = (f32x4)0.f;

  const char* Asc = (const char*)As;
  const char* Bsc = (const char*)Bs;
  char* AsW = (char*)As + (tid & 192) * 16;   // wave-uniform LDS stage base
  char* BsW = (char*)Bs + (tid & 192) * 16;

  for (int k0 = 0; k0 < K; k0 += 64) {
#pragma unroll
    for (int i = 0; i < 4; ++i) {
      int row = tr + i * 32;
      int sc = sc_lin ^ (row & 7);
      gload_lds16(A + (size_t)(bm + row) * K + k0 + sc * 8, AsW + i * 4096);
      gload_lds16(W + (size_t)(bn + row) * K + k0 + sc * 8, BsW + i * 4096);
    }
    __syncthreads();
#pragma unroll
    for (int kk = 0; kk < 2; ++kk) {
      const int colb = kk * 64 + hi4 * 16;
      bf16x8 av[4], bv[4];
#pragma unroll
      for (int m = 0; m < 4; ++m)
        av[m] = *(const bf16x8*)(Asc + (arow + m * 16) * 128 + (colb ^ amask));
#pragma unroll
      for (int n = 0; n < 4; ++n)
        bv[n] = *(const bf16x8*)(Bsc + (brow + n * 16) * 128 + (colb ^ bmask));
#pragma unroll
      for (int m = 0; m < 4; ++m)
#pragma unroll
        for (int n = 0; n < 4; ++n)
          acc[m][n] = __builtin_amdgcn_mfma_f32_16x16x32_bf16(av[m], bv[n], acc[m][n], 0, 0, 0);
    }
    __syncthreads();
  }

  // epilogue: C/D layout col=lane&15, row=(lane>>4)*4+reg
#pragma unroll
  for (int n = 0; n < 4; ++n) {
    const int col = bn + wc * 64 + n * 16 + lo16;
    const float bv = BIAS ? bias[col] : 0.f;
#pragma unroll
    for (int m = 0; m < 4; ++m) {
      const int rowb = bm + wr * 64 + m * 16 + hi4 * 4;
#pragma unroll
      for (int j = 0; j < 4; ++j) {
        float v = acc[m][n][j] + bv;
        if (RELU) v = fmaxf(v, 0.f);
        if (OUTBF) ((unsigned short*)Cout)[(size_t)(rowb + j) * N + col] = f2bf(v);
        else       ((float*)Cout)[(size_t)(rowb + j) * N + col] = v;
      }
    }
  }
}

// ---------------- attention: one wave per (board, head); bf16 in/out ----------
__global__ __launch_bounds__(64) void attn_kernel(const unsigned short* __restrict__ qkv,
                                                  unsigned short* __restrict__ o) {
  __shared__ float Ks[64][32];
  __shared__ float Vs[64][32];
  int bh = blockIdx.x;
  int b = bh >> 3, h = bh & 7;
  int t = threadIdx.x;
  const size_t base = (size_t)b * 64 * 768 + (size_t)h * 32;

  int rq = t >> 2;            // 0..15
  int cq = (t & 3) * 8;       // 0..24
#pragma unroll
  for (int p = 0; p < 4; ++p) {
    int r = p * 16 + rq;
    u16x8 kv = *(const u16x8*)(qkv + base + (size_t)r * 768 + 256 + cq);
    u16x8 vv = *(const u16x8*)(qkv + base + (size_t)r * 768 + 512 + cq);
#pragma unroll
    for (int j = 0; j < 8; ++j) { Ks[r][cq + j] = bf2f(kv[j]); Vs[r][cq + j] = bf2f(vv[j]); }
  }
  float q[32];
#pragma unroll
  for (int c = 0; c < 4; ++c) {
    u16x8 qv = *(const u16x8*)(qkv + base + (size_t)t * 768 + c * 8);
#pragma unroll
    for (int j = 0; j < 8; ++j) q[c * 8 + j] = bf2f(qv[j]);
  }
  __syncthreads();

  const float scale = 0.17677669529663687f;  // 1/sqrt(32)
  float sc[64];
#pragma unroll
  for (int jr = 0; jr < 64; ++jr) {
    float s = 0.f;
#pragma unroll
    for (int d = 0; d < 32; ++d) s += q[d] * Ks[jr][d];
    sc[jr] = s * scale;
  }
  float m = sc[0];
#pragma unroll
  for (int jr = 1; jr < 64; ++jr) m = fmaxf(m, sc[jr]);
  float sum = 0.f;
#pragma unroll
  for (int jr = 0; jr < 64; ++jr) { sc[jr] = expf(sc[jr] - m); sum += sc[jr]; }
  float inv = 1.f / sum;

  float oa[32];
#pragma unroll
  for (int d = 0; d < 32; ++d) oa[d] = 0.f;
#pragma unroll
  for (int jr = 0; jr < 64; ++jr) {
    float p = sc[jr];
#pragma unroll
    for (int d = 0; d < 32; ++d) oa[d] += p * Vs[jr][d];
  }
  unsigned short* op = o + (size_t)(b * 64 + t) * DM + h * 32;
#pragma unroll
  for (int c = 0; c < 4; ++c) {
    u16x8 r;
#pragma unroll
    for (int j = 0; j < 8; ++j) r[j] = f2bf(oa[c * 8 + j] * inv);
    *(u16x8*)(op + c * 8) = r;
  }
}

// ------------- residual add + LayerNorm (writes f32 + bf16) -------------
__global__ __launch_bounds__(256) void ln_kernel(const float* __restrict__ xin,
                                                 const float* __restrict__ delta,
                                                 const float* __restrict__ g,
                                                 const float* __restrict__ beta,
                                                 float* __restrict__ xout,
                                                 unsigned short* __restrict__ xbf, int nrows) {
  int row = (blockIdx.x * 256 + threadIdx.x) >> 6;
  int lane = threadIdx.x & 63;
  if (row >= nrows) return;
  float4 xv = *(const float4*)(xin + (size_t)row * DM + lane * 4);
  float4 dv = *(const float4*)(delta + (size_t)row * DM + lane * 4);
  float v0 = xv.x + dv.x, v1 = xv.y + dv.y, v2 = xv.z + dv.z, v3 = xv.w + dv.w;
  float s1 = v0 + v1 + v2 + v3;
  float s2 = v0 * v0 + v1 * v1 + v2 * v2 + v3 * v3;
#pragma unroll
  for (int off = 32; off; off >>= 1) {
    s1 += __shfl_xor(s1, off);
    s2 += __shfl_xor(s2, off);
  }
  float mean = s1 * (1.f / DM);
  float var = s2 * (1.f / DM) - mean * mean;
  float r = rsqrtf(var + 1e-5f);
  float4 gv = *(const float4*)(g + lane * 4);
  float4 bv = *(const float4*)(beta + lane * 4);
  float4 outv;
  outv.x = (v0 - mean) * r * gv.x + bv.x;
  outv.y = (v1 - mean) * r * gv.y + bv.y;
  outv.z = (v2 - mean) * r * gv.z + bv.z;
  outv.w = (v3 - mean) * r * gv.w + bv.w;
  *(float4*)(xout + (size_t)row * DM + lane * 4) = outv;
  ushort4 h; h.x = f2bf(outv.x); h.y = f2bf(outv.y); h.z = f2bf(outv.z); h.w = f2bf(outv.w);
  *(ushort4*)(xbf + (size_t)row * DM + lane * 4) = h;
}

// ---------------- fp32 GEMM (small head matmuls) ----------------
template<bool BIAS, bool RELU>
__global__ __launch_bounds__(256) void gemm_f32(
    const float* __restrict__ A, const float* __restrict__ W,
    const float* __restrict__ bias, float* __restrict__ C,
    int M, int N, int K)
{
  __shared__ float As[32][68];
  __shared__ float Bs[32][68];
  const int bm = blockIdx.x * 64;
  const int bn = blockIdx.y * 64;
  const int tid = threadIdx.x;
  const int lr = tid >> 3;
  const int lc = (tid & 7) * 4;
  const int ty = tid >> 4;
  const int tx = tid & 15;
  float acc[4][4] = {{0.f}};

  for (int k0 = 0; k0 < K; k0 += 32) {
#pragma unroll
    for (int p = 0; p < 2; ++p) {
      int r = lr + p * 32;
      float4 av = *(const float4*)(A + (size_t)(bm + r) * K + k0 + lc);
      As[lc + 0][r] = av.x; As[lc + 1][r] = av.y; As[lc + 2][r] = av.z; As[lc + 3][r] = av.w;
      float4 wv = *(const float4*)(W + (size_t)(bn + r) * K + k0 + lc);
      Bs[lc + 0][r] = wv.x; Bs[lc + 1][r] = wv.y; Bs[lc + 2][r] = wv.z; Bs[lc + 3][r] = wv.w;
    }
    __syncthreads();
#pragma unroll
    for (int k = 0; k < 32; ++k) {
      float4 a = *(const float4*)&As[k][ty * 4];
      float4 b = *(const float4*)&Bs[k][tx * 4];
      acc[0][0] += a.x * b.x; acc[0][1] += a.x * b.y; acc[0][2] += a.x * b.z; acc[0][3] += a.x * b.w;
      acc[1][0] += a.y * b.x; acc[1][1] += a.y * b.y; acc[1][2] += a.y * b.z; acc[1][3] += a.y * b.w;
      acc[2][0] += a.z * b.x; acc[2][1] += a.z * b.y; acc[2][2] += a.z * b.z; acc[2][3] += a.z * b.w;
      acc[3][0] += a.w * b.x; acc[3][1] += a.w * b.y; acc[3][2] += a.w * b.z; acc[3][3] += a.w * b.w;
    }
    __syncthreads();
  }

  float4 bv = make_float4(0.f, 0.f, 0.f, 0.f);
  if (BIAS) bv = *(const float4*)(bias + bn + tx * 4);
#pragma unroll
  for (int i = 0; i < 4; ++i) {
    float4 r;
    r.x = acc[i][0] + bv.x; r.y = acc[i][1] + bv.y;
    r.z = acc[i][2] + bv.z; r.w = acc[i][3] + bv.w;
    if (RELU) {
      r.x = fmaxf(r.x, 0.f); r.y = fmaxf(r.y, 0.f);
      r.z = fmaxf(r.z, 0.f); r.w = fmaxf(r.w, 0.f);
    }
    *(float4*)(C + (size_t)(bm + ty * 4 + i) * N + bn + tx * 4) = r;
  }
}

// ---------------- mean-pool over 64 tokens ----------------
__global__ void pool_kernel(const float* __restrict__ x, float* __restrict__ pooled, int nb) {
  int g = blockIdx.x * 256 + threadIdx.x;
  if (g >= nb * DM) return;
  int b = g >> 8, d = g & 255;
  const float* p = x + (size_t)b * SEQ * DM + d;
  float s = 0.f;
#pragma unroll
  for (int t = 0; t < SEQ; ++t) s += p[(size_t)t * DM];
  pooled[g] = s * (1.f / SEQ);
}

// ---------------- value head final ----------------
__global__ void value_kernel(const float* __restrict__ h, const float* __restrict__ w,
                             const float* __restrict__ bias, float* __restrict__ out, int nb) {
  int row = (blockIdx.x * 256 + threadIdx.x) >> 6;
  int lane = threadIdx.x & 63;
  if (row >= nb) return;
  float4 hv = *(const float4*)(h + (size_t)row * DM + lane * 4);
  float4 wv = *(const float4*)(w + lane * 4);
  float s = hv.x * wv.x + hv.y * wv.y + hv.z * wv.z + hv.w * wv.w;
#pragma unroll
  for (int off = 32; off; off >>= 1) s += __shfl_xor(s, off);
  if (lane == 0) out[row] = tanhf(s + bias[0]);
}

// ---------------- classification final ----------------
__global__ void cls_kernel(const float* __restrict__ h, const float* __restrict__ w,
                           const float* __restrict__ bias, float* __restrict__ out, int nb) {
  int row = (blockIdx.x * 256 + threadIdx.x) >> 6;
  int lane = threadIdx.x & 63;
  if (row >= nb) return;
  float4 hv = *(const float4*)(h + (size_t)row * DM + lane * 4);
#pragma unroll
  for (int j = 0; j < 3; ++j) {
    float4 wv = *(const float4*)(w + (size_t)j * DM + lane * 4);
    float s = hv.x * wv.x + hv.y * wv.y + hv.z * wv.z + hv.w * wv.w;
#pragma unroll
    for (int off = 32; off; off >>= 1) s += __shfl_xor(s, off);
    if (lane == 0) out[(size_t)row * 3 + j] = s + bias[j];
  }
}

extern "C" void kernel_launch(void* const* d_in, const int* in_sizes, int n_in,
                              void* d_out, int out_size, void* d_ws, size_t ws_size,
                              hipStream_t stream) {
  const float* board = (const float*)d_in[0];
  const float* emb   = (const float*)d_in[1];
  const float* qkv_w = (const float*)d_in[2];
  const float* qkv_b = (const float*)d_in[3];
  const float* out_w = (const float*)d_in[4];
  const float* out_b = (const float*)d_in[5];
  const float* ln1_g = (const float*)d_in[6];
  const float* ln1_b = (const float*)d_in[7];
  const float* ln2_g = (const float*)d_in[8];
  const float* ln2_b = (const float*)d_in[9];
  const float* ff1_w = (const float*)d_in[10];
  const float* ff1_b = (const float*)d_in[11];
  const float* ff2_w = (const float*)d_in[12];
  const float* ff2_b = (const float*)d_in[13];
  const float* vw1 = (const float*)d_in[14];
  const float* vb1 = (const float*)d_in[15];
  const float* vw2 = (const float*)d_in[16];
  const float* vb2 = (const float*)d_in[17];
  const float* pw1 = (const float*)d_in[18];
  const float* pb1 = (const float*)d_in[19];
  const float* pw2 = (const float*)d_in[20];
  const float* pb2 = (const float*)d_in[21];
  const float* cw1 = (const float*)d_in[22];
  const float* cb1 = (const float*)d_in[23];
  const float* cw2 = (const float*)d_in[24];
  const float* cb2 = (const float*)d_in[25];
  (void)in_sizes; (void)n_in; (void)out_size;

  // ---- workspace: header (pe, toks, bf16 weights) + per-chunk region ----
  char* ws = (char*)d_ws;
  float* pe       = (float*)(ws + 0);                 // 64 KB
  int*   toks_all = (int*)  (ws + 65536);             // 1 MB
  unsigned short* qkvw_bf = (unsigned short*)(ws + 1114112);    // 6*768*256
  unsigned short* outw_bf = (unsigned short*)(ws + 3473408);    // 6*256*256
  unsigned short* ff1w_bf = (unsigned short*)(ws + 4259840);    // 6*1024*256
  unsigned short* ff2w_bf = (unsigned short*)(ws + 7405568);    // 6*256*1024
  unsigned short* pw1_bf  = (unsigned short*)(ws + 10551296);   // 1024*16384
  unsigned short* pw2_bf  = (unsigned short*)(ws + 44105728);   // 4096*1024
  const size_t header = 52494336;                     // ≈ 50 MB

  // adaptive chunk: per-chunk bytes = CNT*6656
  int CB = 2048;
  while (CB > 128 && header + (size_t)CB * 64 * 6656 > ws_size) CB >>= 1;
  const int NCH = BB / CB;
  const int CNT = CB * SEQ;

  float*          x_c    = (float*)(ws + header);                  // [CNT,256] f32
  unsigned short* x_bf   = (unsigned short*)(x_c + (size_t)CNT * DM);        // [CNT,256] bf16
  unsigned short* qkv_bf = x_bf + (size_t)CNT * DM;                // [CNT,768] bf16
  unsigned short* o_bf   = qkv_bf + (size_t)CNT * 768;             // [CNT,256] bf16
  unsigned short* mid_bf = o_bf + (size_t)CNT * DM;                // [CNT,1024] bf16
  float*          delta  = (float*)(mid_bf + (size_t)CNT * FFD);   // [CNT,256] f32
  // head overlays (regions free by head time)
  float*          pooled = delta;                                  // [CB,256] f32
  unsigned short* ph_bf  = mid_bf;                                 // [CB,1024] bf16
  float*          vh     = (float*)qkv_bf;                         // [CB,256] f32
  float*          chb    = vh + (size_t)CB * DM;                   // [CB,256] f32

  float* out = (float*)d_out;
  float* value_out  = out;
  float* policy_out = out + BB;
  float* cls_out    = out + BB + (size_t)BB * 4096;

  pe_kernel<<<64, 256, 0, stream>>>(pe);
  tok_kernel<<<NT / 256, 256, 0, stream>>>(board, toks_all);

  // weight conversion (once per launch; ws is re-poisoned each call)
  cvt_kernel<<<(6*768*256/4 + 255)/256, 256, 0, stream>>>(qkv_w, qkvw_bf, 6*768*256/4);
  cvt_kernel<<<(6*256*256/4 + 255)/256, 256, 0, stream>>>(out_w, outw_bf, 6*256*256/4);
  cvt_kernel<<<(6*1024*256/4 + 255)/256, 256, 0, stream>>>(ff1_w, ff1w_bf, 6*1024*256/4);
  cvt_kernel<<<(6*256*1024/4 + 255)/256, 256, 0, stream>>>(ff2_w, ff2w_bf, 6*256*1024/4);
  cvt_kernel<<<(1024*16384/4 + 255)/256, 256, 0, stream>>>(pw1, pw1_bf, 1024*16384/4);
  cvt_kernel<<<(4096*1024/4 + 255)/256, 256, 0, stream>>>(pw2, pw2_bf, 4096*1024/4);

  for (int c = 0; c < NCH; ++c) {
    const int b0 = c * CB;
    const int* toks_c = toks_all + (size_t)b0 * SEQ;

    embed_kernel<<<CNT / 4, 256, 0, stream>>>(toks_c, emb, pe, x_c, x_bf, CNT);

    for (int l = 0; l < NL; ++l) {
      // QKV [CNT,768] bf16
      gemm_bf16<true, false, true><<<dim3(CNT/128, 768/128), 256, 0, stream>>>(
          x_bf, qkvw_bf + (size_t)l * 768 * DM, qkv_b + (size_t)l * 768, qkv_bf, CNT, 768, DM);
      attn_kernel<<<CB * NH, 64, 0, stream>>>(qkv_bf, o_bf);
      // out-proj -> delta f32
      gemm_bf16<false, false, true><<<dim3(CNT/128, DM/128), 256, 0, stream>>>(
          o_bf, outw_bf + (size_t)l * DM * DM, out_b + (size_t)l * DM, delta, CNT, DM, DM);
      ln_kernel<<<CNT / 4, 256, 0, stream>>>(x_c, delta, ln1_g + (size_t)l * DM,
                                             ln1_b + (size_t)l * DM, x_c, x_bf, CNT);
      // FF1 + ReLU -> mid bf16
      gemm_bf16<true, true, true><<<dim3(CNT/128, FFD/128), 256, 0, stream>>>(
          x_bf, ff1w_bf + (size_t)l * FFD * DM, ff1_b + (size_t)l * FFD, mid_bf, CNT, FFD, DM);
      // FF2 -> delta f32
      gemm_bf16<false, false, true><<<dim3(CNT/128, DM/128), 256, 0, stream>>>(
          mid_bf, ff2w_bf + (size_t)l * DM * FFD, ff2_b + (size_t)l * DM, delta, CNT, DM, FFD);
      ln_kernel<<<CNT / 4, 256, 0, stream>>>(x_c, delta, ln2_g + (size_t)l * DM,
                                             ln2_b + (size_t)l * DM, x_c, x_bf, CNT);
    }

    // ---- heads ----
    pool_kernel<<<CB, 256, 0, stream>>>(x_c, pooled, CB);

    gemm_f32<true, true><<<dim3(CB / 64, DM / 64), 256, 0, stream>>>(
        pooled, vw1, vb1, vh, CB, DM, DM);
    value_kernel<<<CB / 4, 256, 0, stream>>>(vh, vw2, vb2, value_out + b0, CB);

    // policy: x_bf flat [CB,16384] @ pw1^T (relu, bf16) ; @ pw2^T -> f32 out
    gemm_bf16<true, true, true><<<dim3(CB/128, FFD/128), 256, 0, stream>>>(
        x_bf, pw1_bf, pb1, ph_bf, CB, FFD, DM * SEQ);
    gemm_bf16<false, false, true><<<dim3(CB/128, 4096/128), 256, 0, stream>>>(
        ph_bf, pw2_bf, pb2, policy_out + (size_t)b0 * 4096, CB, 4096, FFD);

    gemm_f32<true, true><<<dim3(CB / 64, DM / 64), 256, 0, stream>>>(
        pooled, cw1, cb1, chb, CB, DM, DM);
    cls_kernel<<<CB / 4, 256, 0, stream>>>(chb, cw2, cb2, cls_out + (size_t)b0 * 3, CB);
  }
}

// Round 5
// 15813.597 us; speedup vs baseline: 3.3746x; 1.0741x over previous
//
#include <hip/hip_runtime.h>
#include <math.h>

#define BB 4096      // total batch
#define SEQ 64       // tokens per board
#define DM 256       // d_model
#define NH 8
#define HDIM 32
#define NL 6
#define FFD 1024
#define NT (BB*SEQ)

typedef __attribute__((ext_vector_type(8))) short bf16x8;
typedef __attribute__((ext_vector_type(4))) float f32x4;
typedef __attribute__((ext_vector_type(8))) unsigned short u16x8;

__device__ __forceinline__ unsigned short f2bf(float f) {
  unsigned u = __float_as_uint(f);
  unsigned r = u + 0x7FFFu + ((u >> 16) & 1u);   // RNE
  return (unsigned short)(r >> 16);
}
__device__ __forceinline__ float bf2f(unsigned short h) {
  return __uint_as_float(((unsigned)h) << 16);
}
__device__ __forceinline__ void gload_lds16(const void* g, void* l) {
  __builtin_amdgcn_global_load_lds((const __attribute__((address_space(1))) unsigned*)g,
                                   (__attribute__((address_space(3))) unsigned*)l, 16, 0, 0);
}

// ---------------- positional encoding (64 x 256) ----------------
__global__ void pe_kernel(float* __restrict__ pe) {
  int g = blockIdx.x * 256 + threadIdx.x;
  if (g >= SEQ * DM) return;
  int s = g >> 8, d = g & 255;
  int i = s >> 3, j = s & 7;
  float ex = (float)(d & ~1) * (1.0f / DM);
  float dv = powf(10000.0f, ex);
  pe[g] = (d & 1) ? cosf((float)j / dv) : sinf((float)i / dv);
}

// ---------------- tokenizer ----------------
__global__ void tok_kernel(const float* __restrict__ board, int* __restrict__ toks) {
  int n = blockIdx.x * 256 + threadIdx.x;
  if (n >= NT) return;
  int b = n >> 6, s = n & 63;
  const float* p = board + (size_t)b * (14 * 64) + s;
  float mx = p[0]; int idx = 0;
#pragma unroll
  for (int c = 1; c < 14; ++c) {
    float v = p[(size_t)c * 64];
    if (v > mx) { mx = v; idx = c; }
  }
  toks[n] = (mx > 0.0f) ? idx + 1 : 0;
}

// ---------------- weight f32 -> bf16 ----------------
__global__ void cvt_kernel(const float* __restrict__ src, unsigned short* __restrict__ dst, int n4) {
  int g = blockIdx.x * 256 + threadIdx.x;
  if (g >= n4) return;
  float4 v = *(const float4*)(src + (size_t)g * 4);
  ushort4 r;
  r.x = f2bf(v.x); r.y = f2bf(v.y); r.z = f2bf(v.z); r.w = f2bf(v.w);
  *(ushort4*)(dst + (size_t)g * 4) = r;
}

// ---------------- x = emb[tok] + pe  (writes f32 + bf16) ----------------
__global__ void embed_kernel(const int* __restrict__ toks, const float* __restrict__ emb,
                             const float* __restrict__ pe, float* __restrict__ x,
                             unsigned short* __restrict__ xbf, int cnt) {
  int g = blockIdx.x * 256 + threadIdx.x;
  if (g >= cnt * (DM / 4)) return;
  int n = g >> 6, q = g & 63;
  int s = n & 63;
  int tok = toks[n];
  float4 e = *(const float4*)(emb + (size_t)tok * DM + q * 4);
  float4 p = *(const float4*)(pe + (size_t)s * DM + q * 4);
  float4 r; r.x = e.x + p.x; r.y = e.y + p.y; r.z = e.z + p.z; r.w = e.w + p.w;
  *(float4*)(x + (size_t)n * DM + q * 4) = r;
  ushort4 h; h.x = f2bf(r.x); h.y = f2bf(r.y); h.z = f2bf(r.z); h.w = f2bf(r.w);
  *(ushort4*)(xbf + (size_t)n * DM + q * 4) = h;
}

// ============ bf16 MFMA GEMM, 2-phase pipelined (T3/T4-minimal) ============
// C[M,N] = A[M,K]@W[N,K]^T (+bias)(+relu). BM=BN=128, BK=64, 256 thr (4 waves).
// Double-buffered LDS; STAGE(t+1) issued BEFORE compute(t); raw s_barrier +
// counted s_waitcnt vmcnt(8) so next-tile loads stay in flight under MFMA.
// XOR-swizzle (involution byte^=(row&7)<<4) applied on global source + ds_read.
template<bool OUTBF, bool RELU, bool BIAS>
__global__ __launch_bounds__(256) void gemm_bf16(
    const unsigned short* __restrict__ A, const unsigned short* __restrict__ W,
    const float* __restrict__ bias, void* __restrict__ Cout,
    int M, int N, int K)
{
  __shared__ __align__(16) short As[2][128 * 64];   // 2 x 16 KB
  __shared__ __align__(16) short Bs[2][128 * 64];   // 2 x 16 KB
  const int bm = blockIdx.x * 128;
  const int bn = blockIdx.y * 128;
  const int tid = threadIdx.x;
  const int lane = tid & 63;
  const int wave = tid >> 6;
  const int wr = wave >> 1, wc = wave & 1;
  const int lo16 = lane & 15, hi4 = lane >> 4;

  const int tr = tid >> 3;               // staging tile row 0..31 (+32/iter)
  const int sc_lin = tid & 7;            // linear col16
  const int arow = wr * 64 + lo16;
  const int brow = wc * 64 + lo16;
  const int amask = (arow & 7) << 4;
  const int bmask = (brow & 7) << 4;
  const int ldsW = (tid & 192) * 16;     // wave-uniform LDS stage base (bytes)

  f32x4 acc[4][4];
#pragma unroll
  for (int m = 0; m < 4; ++m)
#pragma unroll
    for (int n = 0; n < 4; ++n) acc[m][n] = (f32x4)0.f;

  const int nk = K >> 6;

  // stage one K-tile (8 gload_lds per thread: 4 A + 4 B)
  auto STAGE = [&](int buf, int k0) {
#pragma unroll
    for (int i = 0; i < 4; ++i) {
      int row = tr + i * 32;
      int sc = sc_lin ^ (row & 7);
      gload_lds16(A + (size_t)(bm + row) * K + k0 + sc * 8,
                  (char*)As[buf] + ldsW + i * 4096);
      gload_lds16(W + (size_t)(bn + row) * K + k0 + sc * 8,
                  (char*)Bs[buf] + ldsW + i * 4096);
    }
  };

  STAGE(0, 0);
  for (int t = 0; t < nk; ++t) {
    const int cur = t & 1;
    if (t + 1 < nk) {
      STAGE(cur ^ 1, (t + 1) << 6);
      asm volatile("s_waitcnt vmcnt(8)" ::: "memory");  // tile t's 8 done; t+1 in flight
    } else {
      asm volatile("s_waitcnt vmcnt(0)" ::: "memory");
    }
    __builtin_amdgcn_s_barrier();

    const char* Asc = (const char*)As[cur];
    const char* Bsc = (const char*)Bs[cur];
#pragma unroll
    for (int kk = 0; kk < 2; ++kk) {
      const int colb = kk * 64 + hi4 * 16;
      bf16x8 av[4], bv[4];
#pragma unroll
      for (int m = 0; m < 4; ++m)
        av[m] = *(const bf16x8*)(Asc + (arow + m * 16) * 128 + (colb ^ amask));
#pragma unroll
      for (int n = 0; n < 4; ++n)
        bv[n] = *(const bf16x8*)(Bsc + (brow + n * 16) * 128 + (colb ^ bmask));
#pragma unroll
      for (int m = 0; m < 4; ++m)
#pragma unroll
        for (int n = 0; n < 4; ++n)
          acc[m][n] = __builtin_amdgcn_mfma_f32_16x16x32_bf16(av[m], bv[n], acc[m][n], 0, 0, 0);
    }
    // all ds_reads consumed by MFMAs above (compiler lgkmcnt) => safe to let
    // other waves re-stage this buffer after the barrier.
    __builtin_amdgcn_s_barrier();
  }

  // epilogue: C/D layout col=lane&15, row=(lane>>4)*4+reg
#pragma unroll
  for (int n = 0; n < 4; ++n) {
    const int col = bn + wc * 64 + n * 16 + lo16;
    const float bv = BIAS ? bias[col] : 0.f;
#pragma unroll
    for (int m = 0; m < 4; ++m) {
      const int rowb = bm + wr * 64 + m * 16 + hi4 * 4;
#pragma unroll
      for (int j = 0; j < 4; ++j) {
        float v = acc[m][n][j] + bv;
        if (RELU) v = fmaxf(v, 0.f);
        if (OUTBF) ((unsigned short*)Cout)[(size_t)(rowb + j) * N + col] = f2bf(v);
        else       ((float*)Cout)[(size_t)(rowb + j) * N + col] = v;
      }
    }
  }
}

// ---------------- attention: one wave per (board, head); bf16 in/out ----------
__global__ __launch_bounds__(64) void attn_kernel(const unsigned short* __restrict__ qkv,
                                                  unsigned short* __restrict__ o) {
  __shared__ float Ks[64][32];
  __shared__ float Vs[64][32];
  int bh = blockIdx.x;
  int b = bh >> 3, h = bh & 7;
  int t = threadIdx.x;
  const size_t base = (size_t)b * 64 * 768 + (size_t)h * 32;

  int rq = t >> 2;            // 0..15
  int cq = (t & 3) * 8;       // 0..24
#pragma unroll
  for (int p = 0; p < 4; ++p) {
    int r = p * 16 + rq;
    u16x8 kv = *(const u16x8*)(qkv + base + (size_t)r * 768 + 256 + cq);
    u16x8 vv = *(const u16x8*)(qkv + base + (size_t)r * 768 + 512 + cq);
#pragma unroll
    for (int j = 0; j < 8; ++j) { Ks[r][cq + j] = bf2f(kv[j]); Vs[r][cq + j] = bf2f(vv[j]); }
  }
  float q[32];
#pragma unroll
  for (int c = 0; c < 4; ++c) {
    u16x8 qv = *(const u16x8*)(qkv + base + (size_t)t * 768 + c * 8);
#pragma unroll
    for (int j = 0; j < 8; ++j) q[c * 8 + j] = bf2f(qv[j]);
  }
  __syncthreads();

  const float scale = 0.17677669529663687f;  // 1/sqrt(32)
  float sc[64];
#pragma unroll
  for (int jr = 0; jr < 64; ++jr) {
    float s = 0.f;
#pragma unroll
    for (int d = 0; d < 32; ++d) s += q[d] * Ks[jr][d];
    sc[jr] = s * scale;
  }
  float m = sc[0];
#pragma unroll
  for (int jr = 1; jr < 64; ++jr) m = fmaxf(m, sc[jr]);
  float sum = 0.f;
#pragma unroll
  for (int jr = 0; jr < 64; ++jr) { sc[jr] = expf(sc[jr] - m); sum += sc[jr]; }
  float inv = 1.f / sum;

  float oa[32];
#pragma unroll
  for (int d = 0; d < 32; ++d) oa[d] = 0.f;
#pragma unroll
  for (int jr = 0; jr < 64; ++jr) {
    float p = sc[jr];
#pragma unroll
    for (int d = 0; d < 32; ++d) oa[d] += p * Vs[jr][d];
  }
  unsigned short* op = o + (size_t)(b * 64 + t) * DM + h * 32;
#pragma unroll
  for (int c = 0; c < 4; ++c) {
    u16x8 r;
#pragma unroll
    for (int j = 0; j < 8; ++j) r[j] = f2bf(oa[c * 8 + j] * inv);
    *(u16x8*)(op + c * 8) = r;
  }
}

// ------------- residual add + LayerNorm (writes f32 + bf16) -------------
__global__ __launch_bounds__(256) void ln_kernel(const float* __restrict__ xin,
                                                 const float* __restrict__ delta,
                                                 const float* __restrict__ g,
                                                 const float* __restrict__ beta,
                                                 float* __restrict__ xout,
                                                 unsigned short* __restrict__ xbf, int nrows) {
  int row = (blockIdx.x * 256 + threadIdx.x) >> 6;
  int lane = threadIdx.x & 63;
  if (row >= nrows) return;
  float4 xv = *(const float4*)(xin + (size_t)row * DM + lane * 4);
  float4 dv = *(const float4*)(delta + (size_t)row * DM + lane * 4);
  float v0 = xv.x + dv.x, v1 = xv.y + dv.y, v2 = xv.z + dv.z, v3 = xv.w + dv.w;
  float s1 = v0 + v1 + v2 + v3;
  float s2 = v0 * v0 + v1 * v1 + v2 * v2 + v3 * v3;
#pragma unroll
  for (int off = 32; off; off >>= 1) {
    s1 += __shfl_xor(s1, off);
    s2 += __shfl_xor(s2, off);
  }
  float mean = s1 * (1.f / DM);
  float var = s2 * (1.f / DM) - mean * mean;
  float r = rsqrtf(var + 1e-5f);
  float4 gv = *(const float4*)(g + lane * 4);
  float4 bv = *(const float4*)(beta + lane * 4);
  float4 outv;
  outv.x = (v0 - mean) * r * gv.x + bv.x;
  outv.y = (v1 - mean) * r * gv.y + bv.y;
  outv.z = (v2 - mean) * r * gv.z + bv.z;
  outv.w = (v3 - mean) * r * gv.w + bv.w;
  *(float4*)(xout + (size_t)row * DM + lane * 4) = outv;
  ushort4 h; h.x = f2bf(outv.x); h.y = f2bf(outv.y); h.z = f2bf(outv.z); h.w = f2bf(outv.w);
  *(ushort4*)(xbf + (size_t)row * DM + lane * 4) = h;
}

// ---------------- fp32 GEMM (small head matmuls) ----------------
template<bool BIAS, bool RELU>
__global__ __launch_bounds__(256) void gemm_f32(
    const float* __restrict__ A, const float* __restrict__ W,
    const float* __restrict__ bias, float* __restrict__ C,
    int M, int N, int K)
{
  __shared__ float As[32][68];
  __shared__ float Bs[32][68];
  const int bm = blockIdx.x * 64;
  const int bn = blockIdx.y * 64;
  const int tid = threadIdx.x;
  const int lr = tid >> 3;
  const int lc = (tid & 7) * 4;
  const int ty = tid >> 4;
  const int tx = tid & 15;
  float acc[4][4] = {{0.f}};

  for (int k0 = 0; k0 < K; k0 += 32) {
#pragma unroll
    for (int p = 0; p < 2; ++p) {
      int r = lr + p * 32;
      float4 av = *(const float4*)(A + (size_t)(bm + r) * K + k0 + lc);
      As[lc + 0][r] = av.x; As[lc + 1][r] = av.y; As[lc + 2][r] = av.z; As[lc + 3][r] = av.w;
      float4 wv = *(const float4*)(W + (size_t)(bn + r) * K + k0 + lc);
      Bs[lc + 0][r] = wv.x; Bs[lc + 1][r] = wv.y; Bs[lc + 2][r] = wv.z; Bs[lc + 3][r] = wv.w;
    }
    __syncthreads();
#pragma unroll
    for (int k = 0; k < 32; ++k) {
      float4 a = *(const float4*)&As[k][ty * 4];
      float4 b = *(const float4*)&Bs[k][tx * 4];
      acc[0][0] += a.x * b.x; acc[0][1] += a.x * b.y; acc[0][2] += a.x * b.z; acc[0][3] += a.x * b.w;
      acc[1][0] += a.y * b.x; acc[1][1] += a.y * b.y; acc[1][2] += a.y * b.z; acc[1][3] += a.y * b.w;
      acc[2][0] += a.z * b.x; acc[2][1] += a.z * b.y; acc[2][2] += a.z * b.z; acc[2][3] += a.z * b.w;
      acc[3][0] += a.w * b.x; acc[3][1] += a.w * b.y; acc[3][2] += a.w * b.z; acc[3][3] += a.w * b.w;
    }
    __syncthreads();
  }

  float4 bv = make_float4(0.f, 0.f, 0.f, 0.f);
  if (BIAS) bv = *(const float4*)(bias + bn + tx * 4);
#pragma unroll
  for (int i = 0; i < 4; ++i) {
    float4 r;
    r.x = acc[i][0] + bv.x; r.y = acc[i][1] + bv.y;
    r.z = acc[i][2] + bv.z; r.w = acc[i][3] + bv.w;
    if (RELU) {
      r.x = fmaxf(r.x, 0.f); r.y = fmaxf(r.y, 0.f);
      r.z = fmaxf(r.z, 0.f); r.w = fmaxf(r.w, 0.f);
    }
    *(float4*)(C + (size_t)(bm + ty * 4 + i) * N + bn + tx * 4) = r;
  }
}

// ---------------- mean-pool over 64 tokens ----------------
__global__ void pool_kernel(const float* __restrict__ x, float* __restrict__ pooled, int nb) {
  int g = blockIdx.x * 256 + threadIdx.x;
  if (g >= nb * DM) return;
  int b = g >> 8, d = g & 255;
  const float* p = x + (size_t)b * SEQ * DM + d;
  float s = 0.f;
#pragma unroll
  for (int t = 0; t < SEQ; ++t) s += p[(size_t)t * DM];
  pooled[g] = s * (1.f / SEQ);
}

// ---------------- value head final ----------------
__global__ void value_kernel(const float* __restrict__ h, const float* __restrict__ w,
                             const float* __restrict__ bias, float* __restrict__ out, int nb) {
  int row = (blockIdx.x * 256 + threadIdx.x) >> 6;
  int lane = threadIdx.x & 63;
  if (row >= nb) return;
  float4 hv = *(const float4*)(h + (size_t)row * DM + lane * 4);
  float4 wv = *(const float4*)(w + lane * 4);
  float s = hv.x * wv.x + hv.y * wv.y + hv.z * wv.z + hv.w * wv.w;
#pragma unroll
  for (int off = 32; off; off >>= 1) s += __shfl_xor(s, off);
  if (lane == 0) out[row] = tanhf(s + bias[0]);
}

// ---------------- classification final ----------------
__global__ void cls_kernel(const float* __restrict__ h, const float* __restrict__ w,
                           const float* __restrict__ bias, float* __restrict__ out, int nb) {
  int row = (blockIdx.x * 256 + threadIdx.x) >> 6;
  int lane = threadIdx.x & 63;
  if (row >= nb) return;
  float4 hv = *(const float4*)(h + (size_t)row * DM + lane * 4);
#pragma unroll
  for (int j = 0; j < 3; ++j) {
    float4 wv = *(const float4*)(w + (size_t)j * DM + lane * 4);
    float s = hv.x * wv.x + hv.y * wv.y + hv.z * wv.z + hv.w * wv.w;
#pragma unroll
    for (int off = 32; off; off >>= 1) s += __shfl_xor(s, off);
    if (lane == 0) out[(size_t)row * 3 + j] = s + bias[j];
  }
}

extern "C" void kernel_launch(void* const* d_in, const int* in_sizes, int n_in,
                              void* d_out, int out_size, void* d_ws, size_t ws_size,
                              hipStream_t stream) {
  const float* board = (const float*)d_in[0];
  const float* emb   = (const float*)d_in[1];
  const float* qkv_w = (const float*)d_in[2];
  const float* qkv_b = (const float*)d_in[3];
  const float* out_w = (const float*)d_in[4];
  const float* out_b = (const float*)d_in[5];
  const float* ln1_g = (const float*)d_in[6];
  const float* ln1_b = (const float*)d_in[7];
  const float* ln2_g = (const float*)d_in[8];
  const float* ln2_b = (const float*)d_in[9];
  const float* ff1_w = (const float*)d_in[10];
  const float* ff1_b = (const float*)d_in[11];
  const float* ff2_w = (const float*)d_in[12];
  const float* ff2_b = (const float*)d_in[13];
  const float* vw1 = (const float*)d_in[14];
  const float* vb1 = (const float*)d_in[15];
  const float* vw2 = (const float*)d_in[16];
  const float* vb2 = (const float*)d_in[17];
  const float* pw1 = (const float*)d_in[18];
  const float* pb1 = (const float*)d_in[19];
  const float* pw2 = (const float*)d_in[20];
  const float* pb2 = (const float*)d_in[21];
  const float* cw1 = (const float*)d_in[22];
  const float* cb1 = (const float*)d_in[23];
  const float* cw2 = (const float*)d_in[24];
  const float* cb2 = (const float*)d_in[25];
  (void)in_sizes; (void)n_in; (void)out_size;

  // ---- workspace: header (pe, toks, bf16 weights) + per-chunk region ----
  char* ws = (char*)d_ws;
  float* pe       = (float*)(ws + 0);                 // 64 KB
  int*   toks_all = (int*)  (ws + 65536);             // 1 MB
  unsigned short* qkvw_bf = (unsigned short*)(ws + 1114112);    // 6*768*256
  unsigned short* outw_bf = (unsigned short*)(ws + 3473408);    // 6*256*256
  unsigned short* ff1w_bf = (unsigned short*)(ws + 4259840);    // 6*1024*256
  unsigned short* ff2w_bf = (unsigned short*)(ws + 7405568);    // 6*256*1024
  unsigned short* pw1_bf  = (unsigned short*)(ws + 10551296);   // 1024*16384
  unsigned short* pw2_bf  = (unsigned short*)(ws + 44105728);   // 4096*1024
  const size_t header = 52494336;                     // ≈ 50 MB

  // adaptive chunk: per-chunk bytes = CNT*6656
  int CB = 2048;
  while (CB > 128 && header + (size_t)CB * 64 * 6656 > ws_size) CB >>= 1;
  const int NCH = BB / CB;
  const int CNT = CB * SEQ;

  float*          x_c    = (float*)(ws + header);                  // [CNT,256] f32
  unsigned short* x_bf   = (unsigned short*)(x_c + (size_t)CNT * DM);        // [CNT,256] bf16
  unsigned short* qkv_bf = x_bf + (size_t)CNT * DM;                // [CNT,768] bf16
  unsigned short* o_bf   = qkv_bf + (size_t)CNT * 768;             // [CNT,256] bf16
  unsigned short* mid_bf = o_bf + (size_t)CNT * DM;                // [CNT,1024] bf16
  float*          delta  = (float*)(mid_bf + (size_t)CNT * FFD);   // [CNT,256] f32
  // head overlays (regions free by head time)
  float*          pooled = delta;                                  // [CB,256] f32
  unsigned short* ph_bf  = mid_bf;                                 // [CB,1024] bf16
  float*          vh     = (float*)qkv_bf;                         // [CB,256] f32
  float*          chb    = vh + (size_t)CB * DM;                   // [CB,256] f32

  float* out = (float*)d_out;
  float* value_out  = out;
  float* policy_out = out + BB;
  float* cls_out    = out + BB + (size_t)BB * 4096;

  pe_kernel<<<64, 256, 0, stream>>>(pe);
  tok_kernel<<<NT / 256, 256, 0, stream>>>(board, toks_all);

  // weight conversion (once per launch; ws is re-poisoned each call)
  cvt_kernel<<<(6*768*256/4 + 255)/256, 256, 0, stream>>>(qkv_w, qkvw_bf, 6*768*256/4);
  cvt_kernel<<<(6*256*256/4 + 255)/256, 256, 0, stream>>>(out_w, outw_bf, 6*256*256/4);
  cvt_kernel<<<(6*1024*256/4 + 255)/256, 256, 0, stream>>>(ff1_w, ff1w_bf, 6*1024*256/4);
  cvt_kernel<<<(6*256*1024/4 + 255)/256, 256, 0, stream>>>(ff2_w, ff2w_bf, 6*256*1024/4);
  cvt_kernel<<<(1024*16384/4 + 255)/256, 256, 0, stream>>>(pw1, pw1_bf, 1024*16384/4);
  cvt_kernel<<<(4096*1024/4 + 255)/256, 256, 0, stream>>>(pw2, pw2_bf, 4096*1024/4);

  for (int c = 0; c < NCH; ++c) {
    const int b0 = c * CB;
    const int* toks_c = toks_all + (size_t)b0 * SEQ;

    embed_kernel<<<CNT / 4, 256, 0, stream>>>(toks_c, emb, pe, x_c, x_bf, CNT);

    for (int l = 0; l < NL; ++l) {
      // QKV [CNT,768] bf16
      gemm_bf16<true, false, true><<<dim3(CNT/128, 768/128), 256, 0, stream>>>(
          x_bf, qkvw_bf + (size_t)l * 768 * DM, qkv_b + (size_t)l * 768, qkv_bf, CNT, 768, DM);
      attn_kernel<<<CB * NH, 64, 0, stream>>>(qkv_bf, o_bf);
      // out-proj -> delta f32
      gemm_bf16<false, false, true><<<dim3(CNT/128, DM/128), 256, 0, stream>>>(
          o_bf, outw_bf + (size_t)l * DM * DM, out_b + (size_t)l * DM, delta, CNT, DM, DM);
      ln_kernel<<<CNT / 4, 256, 0, stream>>>(x_c, delta, ln1_g + (size_t)l * DM,
                                             ln1_b + (size_t)l * DM, x_c, x_bf, CNT);
      // FF1 + ReLU -> mid bf16
      gemm_bf16<true, true, true><<<dim3(CNT/128, FFD/128), 256, 0, stream>>>(
          x_bf, ff1w_bf + (size_t)l * FFD * DM, ff1_b + (size_t)l * FFD, mid_bf, CNT, FFD, DM);
      // FF2 -> delta f32
      gemm_bf16<false, false, true><<<dim3(CNT/128, DM/128), 256, 0, stream>>>(
          mid_bf, ff2w_bf + (size_t)l * DM * FFD, ff2_b + (size_t)l * DM, delta, CNT, DM, FFD);
      ln_kernel<<<CNT / 4, 256, 0, stream>>>(x_c, delta, ln2_g + (size_t)l * DM,
                                             ln2_b + (size_t)l * DM, x_c, x_bf, CNT);
    }

    // ---- heads ----
    pool_kernel<<<CB, 256, 0, stream>>>(x_c, pooled, CB);

    gemm_f32<true, true><<<dim3(CB / 64, DM / 64), 256, 0, stream>>>(
        pooled, vw1, vb1, vh, CB, DM, DM);
    value_kernel<<<CB / 4, 256, 0, stream>>>(vh, vw2, vb2, value_out + b0, CB);

    // policy: x_bf flat [CB,16384] @ pw1^T (relu, bf16) ; @ pw2^T -> f32 out
    gemm_bf16<true, true, true><<<dim3(CB/128, FFD/128), 256, 0, stream>>>(
        x_bf, pw1_bf, pb1, ph_bf, CB, FFD, DM * SEQ);
    gemm_bf16<false, false, true><<<dim3(CB/128, 4096/128), 256, 0, stream>>>(
        ph_bf, pw2_bf, pb2, policy_out + (size_t)b0 * 4096, CB, 4096, FFD);

    gemm_f32<true, true><<<dim3(CB / 64, DM / 64), 256, 0, stream>>>(
        pooled, cw1, cb1, chb, CB, DM, DM);
    cls_kernel<<<CB / 4, 256, 0, stream>>>(chb, cw2, cb2, cls_out + (size_t)b0 * 3, CB);
  }
}